// Round 5
// baseline (1721.159 us; speedup 1.0000x reference)
//
#include <hip/hip_runtime.h>
#include <math.h>

#define Bb 32
#define Nn 128
#define Kk 48
#define Ff 256
#define Gg 50
#define Tt 3

__device__ __forceinline__ float ssp_f(float v) {
    return fmaxf(v, 0.f) + log1pf(expf(-fabsf(v))) - 0.69314718055994530942f;
}

#define LDG4(p) (*reinterpret_cast<const float4*>(p))
#define ST4(p, v) (*reinterpret_cast<float4*>(p) = (v))

// dst[4] += s * vv.{x,y,z,w}   (param must NOT be named like a member!)
#define FMA4(dst, s, vv)                      \
    dst[0] = fmaf((s), (vv).x, dst[0]);       \
    dst[1] = fmaf((s), (vv).y, dst[1]);       \
    dst[2] = fmaf((s), (vv).z, dst[2]);       \
    dst[3] = fmaf((s), (vv).w, dst[3]);

// ---------------------------------------------------------------------------
// k_setup: x = embedding[z]; d, fexp, fcut per (b,n,k)
// ---------------------------------------------------------------------------
__global__ __launch_bounds__(256) void k_setup(
    const float* __restrict__ pos, const int* __restrict__ zz,
    const int* __restrict__ nbr, const float* __restrict__ nmask,
    const float* __restrict__ emb,
    float* __restrict__ x, float* __restrict__ fexp, float* __restrict__ fcut)
{
    const int bn = blockIdx.x;
    const int b  = bn >> 7;
    const int t  = threadIdx.x;
    __shared__ float sd[Kk];

    x[bn * Ff + t] = emb[zz[bn] * Ff + t];

    if (t < Kk) {
        int j = nbr[bn * Kk + t];
        float px = pos[bn * 3 + 0], py = pos[bn * 3 + 1], pz = pos[bn * 3 + 2];
        int rj = (b * Nn + j) * 3;
        float dx = pos[rj + 0] - px;
        float dy = pos[rj + 1] - py;
        float dz = pos[rj + 2] - pz;
        float d = sqrtf(fmaf(dx, dx, fmaf(dy, dy, dz * dz)) + 1e-8f);
        sd[t] = d;
        float fc = 0.5f * (cosf(3.14159265358979323846f * d / 5.0f) + 1.0f);
        fc = (d < 5.0f) ? fc : 0.0f;
        fcut[bn * Kk + t] = fc * nmask[bn * Kk + t];
    }
    __syncthreads();

    const float step = 5.0f / 49.0f;
    const float coeff = -0.5f / (step * step);
    for (int i = t; i < Kk * Gg; i += 256) {
        int k = i / Gg, g = i - k * Gg;
        float dd = sd[k] - step * (float)g;
        fexp[bn * (Kk * Gg) + i] = expf(coeff * dd * dd);
    }
}

// ---------------------------------------------------------------------------
// k_y: y = x @ in2f_w[t]   — f-quad × h-split tiling
// ---------------------------------------------------------------------------
__global__ __launch_bounds__(256) void k_y(
    const float* __restrict__ x, const float* __restrict__ w,
    float* __restrict__ y)
{
    const int bn  = blockIdx.x;
    const int tid = threadIdx.x;
    const int tx  = tid & 63;
    const int ty  = tid >> 6;
    const int f4  = tx * 4;

    __shared__ __align__(16) float sx[Ff];
    __shared__ __align__(16) float p4[4][Ff];

    sx[tid] = x[bn * Ff + tid];
    __syncthreads();

    float p[4] = {0.f, 0.f, 0.f, 0.f};
    #pragma unroll 1
    for (int hh = 0; hh < 64; hh += 8) {
        const int h0 = ty * 64 + hh;
        float4 wq[8];
        #pragma unroll
        for (int j = 0; j < 8; ++j)
            wq[j] = LDG4(&w[(h0 + j) * Ff + f4]);
        const float4 a0 = LDG4(&sx[h0]);
        const float4 a1 = LDG4(&sx[h0 + 4]);
        FMA4(p, a0.x, wq[0]); FMA4(p, a0.y, wq[1]);
        FMA4(p, a0.z, wq[2]); FMA4(p, a0.w, wq[3]);
        FMA4(p, a1.x, wq[4]); FMA4(p, a1.y, wq[5]);
        FMA4(p, a1.z, wq[6]); FMA4(p, a1.w, wq[7]);
    }
    *reinterpret_cast<float4*>(&p4[ty][f4]) = make_float4(p[0], p[1], p[2], p[3]);
    __syncthreads();
    y[bn * Ff + tid] = p4[0][tid] + p4[1][tid] + p4[2][tid] + p4[3][tid];
}

// ---------------------------------------------------------------------------
// k_agg2: 2 atoms per block, LDS-staged weights (double-buffered octets),
// K in 4 passes of 12 k/atom. Wave ty: atom = ty>>1, 6 rows per pass.
// ---------------------------------------------------------------------------

// stage load (per-thread 32 B of an 8-row octet) + write + compute steps
#define STG_LOAD(gbase, oct, d0, d1) do {                         \
    const float* _sp = (gbase) + (oct) * 2048 + tid * 8;          \
    d0 = LDG4(_sp); d1 = LDG4(_sp + 4); } while (0)

#define STG_WRITE(bufi, d0, d1) do {                              \
    float* _dp = &stage[bufi][0][0] + tid * 8;                    \
    ST4(_dp, d0); ST4(_dp + 4, d1); } while (0)

#define L1_COMPUTE(bufi, go) do {                                 \
    float4 wq0 = LDG4(&stage[bufi][0][f4]);                       \
    float4 wq1 = LDG4(&stage[bufi][1][f4]);                       \
    float4 wq2 = LDG4(&stage[bufi][2][f4]);                       \
    float4 wq3 = LDG4(&stage[bufi][3][f4]);                       \
    float4 wq4 = LDG4(&stage[bufi][4][f4]);                       \
    float4 wq5 = LDG4(&stage[bufi][5][f4]);                       \
    float4 wq6 = LDG4(&stage[bufi][6][f4]);                       \
    float4 wq7 = LDG4(&stage[bufi][7][f4]);                       \
    _Pragma("unroll")                                             \
    for (int rr = 0; rr < 6; ++rr) {                              \
        const float4 fe0 = LDG4(&sfe[ty * 6 + rr][(go) * 8]);     \
        const float4 fe1 = LDG4(&sfe[ty * 6 + rr][(go) * 8 + 4]); \
        FMA4(h1[rr], fe0.x, wq0); FMA4(h1[rr], fe0.y, wq1);       \
        FMA4(h1[rr], fe0.z, wq2); FMA4(h1[rr], fe0.w, wq3);       \
        FMA4(h1[rr], fe1.x, wq4); FMA4(h1[rr], fe1.y, wq5);       \
        FMA4(h1[rr], fe1.z, wq6); FMA4(h1[rr], fe1.w, wq7);       \
    } } while (0)

#define L2_COMPUTE(bufi, ho) do {                                 \
    float4 wq0 = LDG4(&stage[bufi][0][f4]);                       \
    float4 wq1 = LDG4(&stage[bufi][1][f4]);                       \
    float4 wq2 = LDG4(&stage[bufi][2][f4]);                       \
    float4 wq3 = LDG4(&stage[bufi][3][f4]);                       \
    float4 wq4 = LDG4(&stage[bufi][4][f4]);                       \
    float4 wq5 = LDG4(&stage[bufi][5][f4]);                       \
    float4 wq6 = LDG4(&stage[bufi][6][f4]);                       \
    float4 wq7 = LDG4(&stage[bufi][7][f4]);                       \
    _Pragma("unroll")                                             \
    for (int rr = 0; rr < 6; ++rr) {                              \
        const float4 s0 = LDG4(&un.sH[ty * 6 + rr][(ho) * 8]);    \
        const float4 s1 = LDG4(&un.sH[ty * 6 + rr][(ho) * 8 + 4]);\
        FMA4(acc[rr], s0.x, wq0); FMA4(acc[rr], s0.y, wq1);       \
        FMA4(acc[rr], s0.z, wq2); FMA4(acc[rr], s0.w, wq3);       \
        FMA4(acc[rr], s1.x, wq4); FMA4(acc[rr], s1.y, wq5);       \
        FMA4(acc[rr], s1.z, wq6); FMA4(acc[rr], s1.w, wq7);       \
    } } while (0)

__global__ __launch_bounds__(256, 3) void k_agg2(
    const float* __restrict__ fexp, const float* __restrict__ fcut,
    const int* __restrict__ nbr, const float* __restrict__ y,
    const float* __restrict__ w1, const float* __restrict__ b1,
    const float* __restrict__ w2, const float* __restrict__ b2,
    const float* __restrict__ fw1, const float* __restrict__ fb1,
    const float* __restrict__ fw2, const float* __restrict__ fb2,
    float* __restrict__ x)
{
    const int blk   = blockIdx.x;
    const int bn0   = blk * 2;
    const int bbase = (bn0 >> 7) << 7;     // b * 128
    const int tid   = threadIdx.x;
    const int lane  = tid & 63;
    const int ty    = tid >> 6;
    const int f4    = lane * 4;
    const int atomw = ty >> 1;             // this wave's atom
    const int klw   = (ty & 1) * 6;        // local-k offset within the pass

    __shared__ __align__(16) float stage[2][8][256];    // 16 KB
    __shared__ __align__(16) union PostU {
        float sH[24][256];                               // 24 KB (pass-local H)
        struct {
            float pagg[4][256];                          // 4 KB
            float p4b[4][2][256];                        // 8 KB
            float red[2][256];                           // 2 KB
            float sv[2][256];                            // 2 KB
        } post;
    } un;
    __shared__ __align__(16) float sfe[24][52];          // 4992 B
    __shared__ float scut_s[2][Kk];
    __shared__ int   snbr_s[2][Kk];

    float aggp[4] = {0.f, 0.f, 0.f, 0.f};
    const float4 b1q = LDG4(&b1[f4]);
    const float4 b2q = LDG4(&b2[f4]);

    if (tid < 96) {
        int a = tid / 48, kk = tid - (tid / 48) * 48;
        scut_s[a][kk] = fcut[(bn0 + a) * Kk + kk];
        snbr_s[a][kk] = nbr[(bn0 + a) * Kk + kk];
    }

    #pragma unroll 1
    for (int p = 0; p < 4; ++p) {
        // ---- sfe coop load: 24 rows x 50 gaussians for this pass ----
        #pragma unroll 1
        for (int idx = tid; idx < 1200; idx += 256) {
            int r = idx / 50, g = idx - r * 50;
            int a = r / 12, kl = r - a * 12;
            sfe[r][g] = fexp[(bn0 + a) * (Kk * Gg) + (p * 12 + kl) * Gg + g];
        }

        float4 a0, a1, bv0, bv1;

        // ---- filter layer 1 (staged w1 octets 0..5 + tail g=48,49) ----
        STG_LOAD(w1, 0, a0, a1);
        STG_WRITE(0, a0, a1);
        STG_LOAD(w1, 1, bv0, bv1);
        __syncthreads();                       // sfe + stage0 (+ scut) ready

        float h1[6][4];
        #pragma unroll
        for (int rr = 0; rr < 6; ++rr) {
            h1[rr][0] = b1q.x; h1[rr][1] = b1q.y;
            h1[rr][2] = b1q.z; h1[rr][3] = b1q.w;
        }

        #pragma unroll 1
        for (int pr = 0; pr < 3; ++pr) {
            const int oct = pr * 2;
            { int nx = oct + 2; if (nx > 5) nx = 5; STG_LOAD(w1, nx, a0, a1); }
            STG_WRITE(1, bv0, bv1);
            L1_COMPUTE(0, oct);
            __syncthreads();
            { int nx = oct + 3; if (nx > 5) nx = 5; STG_LOAD(w1, nx, bv0, bv1); }
            STG_WRITE(0, a0, a1);
            L1_COMPUTE(1, oct + 1);
            __syncthreads();
        }

        // tail g = 48, 49 (direct global) + ssp + store H
        {
            const float4 wt0 = LDG4(&w1[48 * Ff + f4]);
            const float4 wt1 = LDG4(&w1[49 * Ff + f4]);
            #pragma unroll
            for (int rr = 0; rr < 6; ++rr) {
                const int r = ty * 6 + rr;
                const float fa = sfe[r][48];
                const float fb = sfe[r][49];
                FMA4(h1[rr], fa, wt0);
                FMA4(h1[rr], fb, wt1);
                float4 hv;
                hv.x = ssp_f(h1[rr][0]); hv.y = ssp_f(h1[rr][1]);
                hv.z = ssp_f(h1[rr][2]); hv.w = ssp_f(h1[rr][3]);
                ST4(&un.sH[r][f4], hv);
            }
        }

        // ---- filter layer 2 (staged w2 octets 0..31) ----
        STG_LOAD(w2, 0, a0, a1);
        STG_WRITE(0, a0, a1);
        STG_LOAD(w2, 1, bv0, bv1);
        __syncthreads();

        float acc[6][4];
        #pragma unroll
        for (int rr = 0; rr < 6; ++rr) {
            acc[rr][0] = 0.f; acc[rr][1] = 0.f;
            acc[rr][2] = 0.f; acc[rr][3] = 0.f;
        }

        #pragma unroll 1
        for (int pr = 0; pr < 16; ++pr) {
            const int oct = pr * 2;
            { int nx = oct + 2; if (nx > 31) nx = 31; STG_LOAD(w2, nx, a0, a1); }
            STG_WRITE(1, bv0, bv1);
            L2_COMPUTE(0, oct);
            __syncthreads();
            { int nx = oct + 3; if (nx > 31) nx = 31; STG_LOAD(w2, nx, bv0, bv1); }
            STG_WRITE(0, a0, a1);
            L2_COMPUTE(1, oct + 1);
            __syncthreads();
        }

        // ---- cutoff + neighbor y gather (accumulate across passes) ----
        #pragma unroll
        for (int rr = 0; rr < 6; ++rr) {
            const int ka = p * 12 + klw + rr;
            const float ct = scut_s[atomw][ka];
            const int  nb = snbr_s[atomw][ka];
            const float4 yv = LDG4(&y[(bbase + nb) * Ff + f4]);
            aggp[0] = fmaf((acc[rr][0] + b2q.x) * ct, yv.x, aggp[0]);
            aggp[1] = fmaf((acc[rr][1] + b2q.y) * ct, yv.y, aggp[1]);
            aggp[2] = fmaf((acc[rr][2] + b2q.z) * ct, yv.z, aggp[2]);
            aggp[3] = fmaf((acc[rr][3] + b2q.w) * ct, yv.w, aggp[3]);
        }
    }

    // ---- cross-wave agg reduce ----
    __syncthreads();                                    // sH region retired
    ST4(&un.post.pagg[ty][f4], make_float4(aggp[0], aggp[1], aggp[2], aggp[3]));
    __syncthreads();
    #pragma unroll
    for (int a = 0; a < 2; ++a)
        un.post.red[a][tid] = un.post.pagg[2 * a][tid] + un.post.pagg[2 * a + 1][tid];
    __syncthreads();

    // ---- f2out matvec 1: wave ty covers h in [64ty, 64ty+64) for BOTH atoms ----
    {
        float pmA[4] = {0.f, 0.f, 0.f, 0.f};
        float pmB[4] = {0.f, 0.f, 0.f, 0.f};
        const int hbase = ty * 64;
        #pragma unroll 1
        for (int oc = 0; oc < 8; ++oc) {
            const int h0 = hbase + oc * 8;
            float4 q0 = LDG4(&fw1[(h0 + 0) * Ff + f4]);
            float4 q1 = LDG4(&fw1[(h0 + 1) * Ff + f4]);
            float4 q2 = LDG4(&fw1[(h0 + 2) * Ff + f4]);
            float4 q3 = LDG4(&fw1[(h0 + 3) * Ff + f4]);
            float4 q4 = LDG4(&fw1[(h0 + 4) * Ff + f4]);
            float4 q5 = LDG4(&fw1[(h0 + 5) * Ff + f4]);
            float4 q6 = LDG4(&fw1[(h0 + 6) * Ff + f4]);
            float4 q7 = LDG4(&fw1[(h0 + 7) * Ff + f4]);
            const float4 rA0 = LDG4(&un.post.red[0][h0]);
            const float4 rA1 = LDG4(&un.post.red[0][h0 + 4]);
            const float4 rB0 = LDG4(&un.post.red[1][h0]);
            const float4 rB1 = LDG4(&un.post.red[1][h0 + 4]);
            FMA4(pmA, rA0.x, q0); FMA4(pmA, rA0.y, q1);
            FMA4(pmA, rA0.z, q2); FMA4(pmA, rA0.w, q3);
            FMA4(pmA, rA1.x, q4); FMA4(pmA, rA1.y, q5);
            FMA4(pmA, rA1.z, q6); FMA4(pmA, rA1.w, q7);
            FMA4(pmB, rB0.x, q0); FMA4(pmB, rB0.y, q1);
            FMA4(pmB, rB0.z, q2); FMA4(pmB, rB0.w, q3);
            FMA4(pmB, rB1.x, q4); FMA4(pmB, rB1.y, q5);
            FMA4(pmB, rB1.z, q6); FMA4(pmB, rB1.w, q7);
        }
        ST4(&un.post.p4b[ty][0][f4], make_float4(pmA[0], pmA[1], pmA[2], pmA[3]));
        ST4(&un.post.p4b[ty][1][f4], make_float4(pmB[0], pmB[1], pmB[2], pmB[3]));
    }
    __syncthreads();
    #pragma unroll
    for (int a = 0; a < 2; ++a) {
        const float uv = un.post.p4b[0][a][tid] + un.post.p4b[1][a][tid]
                       + un.post.p4b[2][a][tid] + un.post.p4b[3][a][tid] + fb1[tid];
        un.post.sv[a][tid] = ssp_f(uv);
    }
    __syncthreads();

    // ---- f2out matvec 2 + residual ----
    {
        float pmA[4] = {0.f, 0.f, 0.f, 0.f};
        float pmB[4] = {0.f, 0.f, 0.f, 0.f};
        const int hbase = ty * 64;
        #pragma unroll 1
        for (int oc = 0; oc < 8; ++oc) {
            const int h0 = hbase + oc * 8;
            float4 q0 = LDG4(&fw2[(h0 + 0) * Ff + f4]);
            float4 q1 = LDG4(&fw2[(h0 + 1) * Ff + f4]);
            float4 q2 = LDG4(&fw2[(h0 + 2) * Ff + f4]);
            float4 q3 = LDG4(&fw2[(h0 + 3) * Ff + f4]);
            float4 q4 = LDG4(&fw2[(h0 + 4) * Ff + f4]);
            float4 q5 = LDG4(&fw2[(h0 + 5) * Ff + f4]);
            float4 q6 = LDG4(&fw2[(h0 + 6) * Ff + f4]);
            float4 q7 = LDG4(&fw2[(h0 + 7) * Ff + f4]);
            const float4 rA0 = LDG4(&un.post.sv[0][h0]);
            const float4 rA1 = LDG4(&un.post.sv[0][h0 + 4]);
            const float4 rB0 = LDG4(&un.post.sv[1][h0]);
            const float4 rB1 = LDG4(&un.post.sv[1][h0 + 4]);
            FMA4(pmA, rA0.x, q0); FMA4(pmA, rA0.y, q1);
            FMA4(pmA, rA0.z, q2); FMA4(pmA, rA0.w, q3);
            FMA4(pmA, rA1.x, q4); FMA4(pmA, rA1.y, q5);
            FMA4(pmA, rA1.z, q6); FMA4(pmA, rA1.w, q7);
            FMA4(pmB, rB0.x, q0); FMA4(pmB, rB0.y, q1);
            FMA4(pmB, rB0.z, q2); FMA4(pmB, rB0.w, q3);
            FMA4(pmB, rB1.x, q4); FMA4(pmB, rB1.y, q5);
            FMA4(pmB, rB1.z, q6); FMA4(pmB, rB1.w, q7);
        }
        ST4(&un.post.p4b[ty][0][f4], make_float4(pmA[0], pmA[1], pmA[2], pmA[3]));
        ST4(&un.post.p4b[ty][1][f4], make_float4(pmB[0], pmB[1], pmB[2], pmB[3]));
    }
    __syncthreads();
    #pragma unroll
    for (int a = 0; a < 2; ++a) {
        const float o = un.post.p4b[0][a][tid] + un.post.p4b[1][a][tid]
                      + un.post.p4b[2][a][tid] + un.post.p4b[3][a][tid] + fb2[tid];
        x[(bn0 + a) * Ff + tid] += o;
    }
}

// ---------------------------------------------------------------------------
// k_head: disp/frac/rep, predictor MLP, masked mean, new_cell, new_pos
// ---------------------------------------------------------------------------
__global__ __launch_bounds__(128) void k_head(
    const float* __restrict__ x, const float* __restrict__ pos,
    const float* __restrict__ cell, const float* __restrict__ amask,
    const float* __restrict__ fdw, const float* __restrict__ fdb,
    const float* __restrict__ pw1, const float* __restrict__ pb1,
    const float* __restrict__ pw2, const float* __restrict__ pb2,
    float* __restrict__ out_pos, float* __restrict__ out_cell)
{
    const int b = blockIdx.x;
    const int n = threadIdx.x;

    __shared__ float sinv[9];
    __shared__ float scell[9];
    __shared__ float snc[9];
    __shared__ float sred[Nn][10];

    if (n == 0) {
        float c[9];
        #pragma unroll
        for (int i = 0; i < 9; ++i) { c[i] = cell[b * 9 + i]; scell[i] = c[i]; }
        float det = c[0] * (c[4] * c[8] - c[5] * c[7])
                  - c[1] * (c[3] * c[8] - c[5] * c[6])
                  + c[2] * (c[3] * c[7] - c[4] * c[6]);
        float id = 1.0f / det;
        sinv[0] = (c[4] * c[8] - c[5] * c[7]) * id;
        sinv[1] = (c[2] * c[7] - c[1] * c[8]) * id;
        sinv[2] = (c[1] * c[5] - c[2] * c[4]) * id;
        sinv[3] = (c[5] * c[6] - c[3] * c[8]) * id;
        sinv[4] = (c[0] * c[8] - c[2] * c[6]) * id;
        sinv[5] = (c[2] * c[3] - c[0] * c[5]) * id;
        sinv[6] = (c[3] * c[7] - c[4] * c[6]) * id;
        sinv[7] = (c[1] * c[6] - c[0] * c[7]) * id;
        sinv[8] = (c[0] * c[4] - c[1] * c[3]) * id;
    }
    __syncthreads();

    float xv0 = 0.f, xv1 = 0.f, xv2 = 0.f;
    const int row = (b * Nn + n) * Ff;
    for (int ff = 0; ff < Ff; ++ff) {
        float xr = x[row + ff];
        xv0 = fmaf(xr, fdw[ff * 3 + 0], xv0);
        xv1 = fmaf(xr, fdw[ff * 3 + 1], xv1);
        xv2 = fmaf(xr, fdw[ff * 3 + 2], xv2);
    }
    float fr[3];
    float dsp[3] = {xv0, xv1, xv2};
    const float p0 = pos[(b * Nn + n) * 3 + 0];
    const float p1 = pos[(b * Nn + n) * 3 + 1];
    const float p2 = pos[(b * Nn + n) * 3 + 2];
    #pragma unroll
    for (int j = 0; j < 3; ++j) {
        float z = 10.0f * (dsp[j] + fdb[j]);
        float s = 1.0f / (1.0f + expf(-z));
        float fx = p0 * sinv[0 * 3 + j] + p1 * sinv[1 * 3 + j] + p2 * sinv[2 * 3 + j] + s;
        fr[j] = fx - floorf(fx);
    }

    float rep[3];
    #pragma unroll
    for (int j = 0; j < 3; ++j)
        rep[j] = fr[0] * scell[0 * 3 + j] + fr[1] * scell[1 * 3 + j] + fr[2] * scell[2 * 3 + j];

    float a6[6];
    #pragma unroll
    for (int i = 0; i < 6; ++i) {
        float uv = rep[0] * pw1[0 * 6 + i] + rep[1] * pw1[1 * 6 + i]
                 + rep[2] * pw1[2 * 6 + i] + pb1[i];
        a6[i] = ssp_f(uv);
    }
    float h9[9];
    #pragma unroll
    for (int o = 0; o < 9; ++o) {
        float uv = pb2[o];
        #pragma unroll
        for (int i = 0; i < 6; ++i) uv = fmaf(a6[i], pw2[i * 9 + o], uv);
        h9[o] = uv;
    }

    const float m = amask[b * Nn + n];
    #pragma unroll
    for (int o = 0; o < 9; ++o) sred[n][o] = h9[o] * m;
    sred[n][9] = m;
    __syncthreads();

    for (int s = 64; s >= 1; s >>= 1) {
        if (n < s) {
            #pragma unroll
            for (int o = 0; o < 10; ++o) sred[n][o] += sred[n + s][o];
        }
        __syncthreads();
    }

    if (n < 9) {
        float na = sred[0][9];
        float yo = sred[0][n] / na;
        float scale = 3.0f * powf(na, 1.0f / 3.0f);
        int r = n / 3, c = n - r * 3;
        float v = scale * (((r == c) ? 1.0f : 0.0f) + yo);
        snc[n] = v;
        out_cell[b * 9 + n] = v;
    }
    __syncthreads();

    #pragma unroll
    for (int j = 0; j < 3; ++j) {
        float v = fr[0] * snc[0 * 3 + j] + fr[1] * snc[1 * 3 + j] + fr[2] * snc[2 * 3 + j];
        out_pos[(b * Nn + n) * 3 + j] = v;
    }
}

// ---------------------------------------------------------------------------
extern "C" void kernel_launch(void* const* d_in, const int* in_sizes, int n_in,
                              void* d_out, int out_size, void* d_ws, size_t ws_size,
                              hipStream_t stream)
{
    const float* positions     = (const float*)d_in[0];
    const float* cell          = (const float*)d_in[1];
    const int*   atomic_nums   = (const int*)  d_in[2];
    const int*   neighbors     = (const int*)  d_in[3];
    const float* neighbor_mask = (const float*)d_in[4];
    const float* atom_mask     = (const float*)d_in[5];
    const float* embedding     = (const float*)d_in[6];
    const float* filt_w1       = (const float*)d_in[7];
    const float* filt_b1       = (const float*)d_in[8];
    const float* filt_w2       = (const float*)d_in[9];
    const float* filt_b2       = (const float*)d_in[10];
    const float* in2f_w        = (const float*)d_in[11];
    const float* f2out_w1      = (const float*)d_in[12];
    const float* f2out_b1      = (const float*)d_in[13];
    const float* f2out_w2      = (const float*)d_in[14];
    const float* f2out_b2      = (const float*)d_in[15];
    const float* fd_w          = (const float*)d_in[16];
    const float* fd_b          = (const float*)d_in[17];
    const float* pred_w1       = (const float*)d_in[18];
    const float* pred_b1       = (const float*)d_in[19];
    const float* pred_w2       = (const float*)d_in[20];
    const float* pred_b2       = (const float*)d_in[21];

    float* ws   = (float*)d_ws;
    float* x    = ws;
    float* y    = x + Bb * Nn * Ff;
    float* fexp = y + Bb * Nn * Ff;
    float* fcut = fexp + Bb * Nn * Kk * Gg;

    float* out_pos  = (float*)d_out;
    float* out_cell = out_pos + Bb * Nn * 3;

    const int BN = Bb * Nn;

    k_setup<<<BN, 256, 0, stream>>>(positions, atomic_nums, neighbors,
                                    neighbor_mask, embedding, x, fexp, fcut);

    for (int t = 0; t < Tt; ++t) {
        k_y<<<BN, 256, 0, stream>>>(x, in2f_w + (size_t)t * Ff * Ff, y);
        k_agg2<<<BN / 2, 256, 0, stream>>>(fexp, fcut, neighbors, y,
                                           filt_w1 + (size_t)t * Gg * Ff,
                                           filt_b1 + (size_t)t * Ff,
                                           filt_w2 + (size_t)t * Ff * Ff,
                                           filt_b2 + (size_t)t * Ff,
                                           f2out_w1 + (size_t)t * Ff * Ff,
                                           f2out_b1 + (size_t)t * Ff,
                                           f2out_w2 + (size_t)t * Ff * Ff,
                                           f2out_b2 + (size_t)t * Ff,
                                           x);
    }

    k_head<<<Bb, 128, 0, stream>>>(x, positions, cell, atom_mask,
                                   fd_w, fd_b, pred_w1, pred_b1, pred_w2, pred_b2,
                                   out_pos, out_cell);
}

// Round 6
// 1517.202 us; speedup vs baseline: 1.1344x; 1.1344x over previous
//
#include <hip/hip_runtime.h>
#include <math.h>

#define Bb 32
#define Nn 128
#define Kk 48
#define Ff 256
#define Gg 50
#define Tt 3

__device__ __forceinline__ float ssp_f(float v) {
    return fmaxf(v, 0.f) + log1pf(expf(-fabsf(v))) - 0.69314718055994530942f;
}

#define LDG4(p) (*reinterpret_cast<const float4*>(p))
#define ST4(p, v) (*reinterpret_cast<float4*>(p) = (v))

// dst[4] += s * vv.{x,y,z,w}   (param must NOT be named like a member!)
#define FMA4(dst, s, vv)                      \
    dst[0] = fmaf((s), (vv).x, dst[0]);       \
    dst[1] = fmaf((s), (vv).y, dst[1]);       \
    dst[2] = fmaf((s), (vv).z, dst[2]);       \
    dst[3] = fmaf((s), (vv).w, dst[3]);

// ---------------------------------------------------------------------------
// k_setup: x = embedding[z]; d, fexp, fcut per (b,n,k)
// ---------------------------------------------------------------------------
__global__ __launch_bounds__(256) void k_setup(
    const float* __restrict__ pos, const int* __restrict__ zz,
    const int* __restrict__ nbr, const float* __restrict__ nmask,
    const float* __restrict__ emb,
    float* __restrict__ x, float* __restrict__ fexp, float* __restrict__ fcut)
{
    const int bn = blockIdx.x;
    const int b  = bn >> 7;
    const int t  = threadIdx.x;
    __shared__ float sd[Kk];

    x[bn * Ff + t] = emb[zz[bn] * Ff + t];

    if (t < Kk) {
        int j = nbr[bn * Kk + t];
        float px = pos[bn * 3 + 0], py = pos[bn * 3 + 1], pz = pos[bn * 3 + 2];
        int rj = (b * Nn + j) * 3;
        float dx = pos[rj + 0] - px;
        float dy = pos[rj + 1] - py;
        float dz = pos[rj + 2] - pz;
        float d = sqrtf(fmaf(dx, dx, fmaf(dy, dy, dz * dz)) + 1e-8f);
        sd[t] = d;
        float fc = 0.5f * (cosf(3.14159265358979323846f * d / 5.0f) + 1.0f);
        fc = (d < 5.0f) ? fc : 0.0f;
        fcut[bn * Kk + t] = fc * nmask[bn * Kk + t];
    }
    __syncthreads();

    const float step = 5.0f / 49.0f;
    const float coeff = -0.5f / (step * step);
    for (int i = t; i < Kk * Gg; i += 256) {
        int k = i / Gg, g = i - k * Gg;
        float dd = sd[k] - step * (float)g;
        fexp[bn * (Kk * Gg) + i] = expf(coeff * dd * dd);
    }
}

// ---------------------------------------------------------------------------
// k_y: y = x @ in2f_w[t]   — f-quad × h-split tiling (w read once per block)
// ---------------------------------------------------------------------------
__global__ __launch_bounds__(256) void k_y(
    const float* __restrict__ x, const float* __restrict__ w,
    float* __restrict__ y)
{
    const int bn  = blockIdx.x;
    const int tid = threadIdx.x;
    const int tx  = tid & 63;
    const int ty  = tid >> 6;
    const int f4  = tx * 4;

    __shared__ __align__(16) float sx[Ff];
    __shared__ __align__(16) float p4[4][Ff];

    sx[tid] = x[bn * Ff + tid];
    __syncthreads();

    float p[4] = {0.f, 0.f, 0.f, 0.f};
    #pragma unroll 1
    for (int hh = 0; hh < 64; hh += 8) {
        const int h0 = ty * 64 + hh;
        float4 wq[8];
        #pragma unroll
        for (int j = 0; j < 8; ++j)
            wq[j] = LDG4(&w[(h0 + j) * Ff + f4]);
        const float4 a0 = LDG4(&sx[h0]);
        const float4 a1 = LDG4(&sx[h0 + 4]);
        FMA4(p, a0.x, wq[0]); FMA4(p, a0.y, wq[1]);
        FMA4(p, a0.z, wq[2]); FMA4(p, a0.w, wq[3]);
        FMA4(p, a1.x, wq[4]); FMA4(p, a1.y, wq[5]);
        FMA4(p, a1.z, wq[6]); FMA4(p, a1.w, wq[7]);
    }
    *reinterpret_cast<float4*>(&p4[ty][f4]) = make_float4(p[0], p[1], p[2], p[3]);
    __syncthreads();
    y[bn * Ff + tid] = p4[0][tid] + p4[1][tid] + p4[2][tid] + p4[3][tid];
}

// ---------------------------------------------------------------------------
// k_agg3: one atom per block. Waves split F (wave w owns f in [64w,64w+64)),
// lanes: kq = lane>>4 (4 k-groups of 12 rows), fq = lane&15 (f-quad).
// Every weight element read exactly once per block. sH reads are 4-address
// LDS broadcasts. kq-partials reduced in-register via __shfl_xor.
// ---------------------------------------------------------------------------
__global__ __launch_bounds__(256, 2) void k_agg3(
    const float* __restrict__ fexp, const float* __restrict__ fcut,
    const int* __restrict__ nbr, const float* __restrict__ y,
    const float* __restrict__ w1, const float* __restrict__ b1,
    const float* __restrict__ w2, const float* __restrict__ b2,
    const float* __restrict__ fw1, const float* __restrict__ fb1,
    const float* __restrict__ fw2, const float* __restrict__ fb2,
    float* __restrict__ x)
{
    const int bn    = blockIdx.x;
    const int bbase = (bn >> 7) << 7;       // b * 128
    const int tid   = threadIdx.x;
    const int w     = tid >> 6;
    const int lane  = tid & 63;
    const int kq    = lane >> 4;            // 0..3  (12 k-rows each)
    const int fq    = lane & 15;            // 0..15 (f-quad)
    const int fbase = w * 64 + fq * 4;
    const int kb    = kq * 12;

    __shared__ __align__(16) float sH[Kk][260];   // 49920 B (+4 pad: 2-way banks)
    __shared__ __align__(16) float sfe[Kk][52];   // 9984 B
    __shared__ __align__(16) float agg_s[Ff];     // 1 KB
    __shared__ __align__(16) float sv_s[Ff];      // 1 KB
    __shared__ float scut[Kk];
    __shared__ int   snbr[Kk];

    // ---- coop loads ----
    for (int idx = tid; idx < Kk * Gg; idx += 256) {
        int r = idx / Gg, g = idx - r * Gg;
        sfe[r][g] = fexp[bn * (Kk * Gg) + idx];
    }
    if (tid < Kk) {
        scut[tid] = fcut[bn * Kk + tid];
        snbr[tid] = nbr[bn * Kk + tid];
    }
    __syncthreads();

    // ---- filter layer 1: h1[rr][j] = ssp(fexp[k,:] @ w1[:,fbase+j] + b1) ----
    float h1[12][4];
    {
        const float4 b1q = LDG4(&b1[fbase]);
        #pragma unroll
        for (int rr = 0; rr < 12; ++rr) {
            h1[rr][0] = b1q.x; h1[rr][1] = b1q.y;
            h1[rr][2] = b1q.z; h1[rr][3] = b1q.w;
        }
        #pragma unroll 1
        for (int c = 0; c < 6; ++c) {
            const int g0 = c * 8;
            float4 wq[8];
            #pragma unroll
            for (int j = 0; j < 8; ++j)
                wq[j] = LDG4(&w1[(g0 + j) * Ff + fbase]);
            #pragma unroll
            for (int rr = 0; rr < 12; ++rr) {
                const float4 fe0 = LDG4(&sfe[kb + rr][g0]);
                const float4 fe1 = LDG4(&sfe[kb + rr][g0 + 4]);
                FMA4(h1[rr], fe0.x, wq[0]); FMA4(h1[rr], fe0.y, wq[1]);
                FMA4(h1[rr], fe0.z, wq[2]); FMA4(h1[rr], fe0.w, wq[3]);
                FMA4(h1[rr], fe1.x, wq[4]); FMA4(h1[rr], fe1.y, wq[5]);
                FMA4(h1[rr], fe1.z, wq[6]); FMA4(h1[rr], fe1.w, wq[7]);
            }
        }
        // tail g = 48, 49
        const float4 wt0 = LDG4(&w1[48 * Ff + fbase]);
        const float4 wt1 = LDG4(&w1[49 * Ff + fbase]);
        #pragma unroll
        for (int rr = 0; rr < 12; ++rr) {
            const float fa = sfe[kb + rr][48];
            const float fb = sfe[kb + rr][49];
            FMA4(h1[rr], fa, wt0);
            FMA4(h1[rr], fb, wt1);
        }
    }
    // ssp + store H (wave writes its own f-slice; all 48 rows across kq)
    #pragma unroll
    for (int rr = 0; rr < 12; ++rr) {
        float4 hv;
        hv.x = ssp_f(h1[rr][0]); hv.y = ssp_f(h1[rr][1]);
        hv.z = ssp_f(h1[rr][2]); hv.w = ssp_f(h1[rr][3]);
        ST4(&sH[kb + rr][fbase], hv);
    }
    __syncthreads();

    // ---- filter layer 2: acc[rr][j] = H[k,:] @ w2[:,fbase+j] ----
    float acc[12][4];
    #pragma unroll
    for (int rr = 0; rr < 12; ++rr) {
        acc[rr][0] = 0.f; acc[rr][1] = 0.f;
        acc[rr][2] = 0.f; acc[rr][3] = 0.f;
    }
    #pragma unroll 1
    for (int c = 0; c < 32; ++c) {
        const int h0 = c * 8;
        float4 wq[8];
        #pragma unroll
        for (int j = 0; j < 8; ++j)
            wq[j] = LDG4(&w2[(h0 + j) * Ff + fbase]);
        #pragma unroll
        for (int rr = 0; rr < 12; ++rr) {
            const float4 s0 = LDG4(&sH[kb + rr][h0]);
            const float4 s1 = LDG4(&sH[kb + rr][h0 + 4]);
            FMA4(acc[rr], s0.x, wq[0]); FMA4(acc[rr], s0.y, wq[1]);
            FMA4(acc[rr], s0.z, wq[2]); FMA4(acc[rr], s0.w, wq[3]);
            FMA4(acc[rr], s1.x, wq[4]); FMA4(acc[rr], s1.y, wq[5]);
            FMA4(acc[rr], s1.z, wq[6]); FMA4(acc[rr], s1.w, wq[7]);
        }
    }

    // ---- cutoff + neighbor y gather (partial over this kq's 12 rows) ----
    float aggp[4] = {0.f, 0.f, 0.f, 0.f};
    {
        const float4 b2q = LDG4(&b2[fbase]);
        #pragma unroll
        for (int rr = 0; rr < 12; ++rr) {
            const float ct = scut[kb + rr];
            const int   nb = snbr[kb + rr];
            const float4 yv = LDG4(&y[(bbase + nb) * Ff + fbase]);
            aggp[0] = fmaf((acc[rr][0] + b2q.x) * ct, yv.x, aggp[0]);
            aggp[1] = fmaf((acc[rr][1] + b2q.y) * ct, yv.y, aggp[1]);
            aggp[2] = fmaf((acc[rr][2] + b2q.z) * ct, yv.z, aggp[2]);
            aggp[3] = fmaf((acc[rr][3] + b2q.w) * ct, yv.w, aggp[3]);
        }
    }
    // in-register reduce across kq (lane bits 4,5)
    #pragma unroll
    for (int j = 0; j < 4; ++j) {
        aggp[j] += __shfl_xor(aggp[j], 16);
        aggp[j] += __shfl_xor(aggp[j], 32);
    }
    if (kq == 0)
        ST4(&agg_s[fbase], make_float4(aggp[0], aggp[1], aggp[2], aggp[3]));
    __syncthreads();

    // ---- f2out matvec 1: kq reinterpreted as h-quarter ----
    {
        float p[4] = {0.f, 0.f, 0.f, 0.f};
        const int hb = kq * 64;
        #pragma unroll 1
        for (int c = 0; c < 8; ++c) {
            const int h0 = hb + c * 8;
            float4 wq[8];
            #pragma unroll
            for (int j = 0; j < 8; ++j)
                wq[j] = LDG4(&fw1[(h0 + j) * Ff + fbase]);
            const float4 a0 = LDG4(&agg_s[h0]);
            const float4 a1 = LDG4(&agg_s[h0 + 4]);
            FMA4(p, a0.x, wq[0]); FMA4(p, a0.y, wq[1]);
            FMA4(p, a0.z, wq[2]); FMA4(p, a0.w, wq[3]);
            FMA4(p, a1.x, wq[4]); FMA4(p, a1.y, wq[5]);
            FMA4(p, a1.z, wq[6]); FMA4(p, a1.w, wq[7]);
        }
        #pragma unroll
        for (int j = 0; j < 4; ++j) {
            p[j] += __shfl_xor(p[j], 16);
            p[j] += __shfl_xor(p[j], 32);
        }
        const float4 fb1q = LDG4(&fb1[fbase]);
        if (kq == 0) {
            float4 sv;
            sv.x = ssp_f(p[0] + fb1q.x); sv.y = ssp_f(p[1] + fb1q.y);
            sv.z = ssp_f(p[2] + fb1q.z); sv.w = ssp_f(p[3] + fb1q.w);
            ST4(&sv_s[fbase], sv);
        }
    }
    __syncthreads();

    // ---- f2out matvec 2 + residual ----
    {
        float p[4] = {0.f, 0.f, 0.f, 0.f};
        const int hb = kq * 64;
        #pragma unroll 1
        for (int c = 0; c < 8; ++c) {
            const int h0 = hb + c * 8;
            float4 wq[8];
            #pragma unroll
            for (int j = 0; j < 8; ++j)
                wq[j] = LDG4(&fw2[(h0 + j) * Ff + fbase]);
            const float4 a0 = LDG4(&sv_s[h0]);
            const float4 a1 = LDG4(&sv_s[h0 + 4]);
            FMA4(p, a0.x, wq[0]); FMA4(p, a0.y, wq[1]);
            FMA4(p, a0.z, wq[2]); FMA4(p, a0.w, wq[3]);
            FMA4(p, a1.x, wq[4]); FMA4(p, a1.y, wq[5]);
            FMA4(p, a1.z, wq[6]); FMA4(p, a1.w, wq[7]);
        }
        #pragma unroll
        for (int j = 0; j < 4; ++j) {
            p[j] += __shfl_xor(p[j], 16);
            p[j] += __shfl_xor(p[j], 32);
        }
        if (kq == 0) {
            const float4 fb2q = LDG4(&fb2[fbase]);
            float4 xv = LDG4(&x[bn * Ff + fbase]);
            xv.x += p[0] + fb2q.x;
            xv.y += p[1] + fb2q.y;
            xv.z += p[2] + fb2q.z;
            xv.w += p[3] + fb2q.w;
            ST4(&x[bn * Ff + fbase], xv);
        }
    }
}

// ---------------------------------------------------------------------------
// k_head: disp/frac/rep, predictor MLP, masked mean, new_cell, new_pos
// ---------------------------------------------------------------------------
__global__ __launch_bounds__(128) void k_head(
    const float* __restrict__ x, const float* __restrict__ pos,
    const float* __restrict__ cell, const float* __restrict__ amask,
    const float* __restrict__ fdw, const float* __restrict__ fdb,
    const float* __restrict__ pw1, const float* __restrict__ pb1,
    const float* __restrict__ pw2, const float* __restrict__ pb2,
    float* __restrict__ out_pos, float* __restrict__ out_cell)
{
    const int b = blockIdx.x;
    const int n = threadIdx.x;

    __shared__ float sinv[9];
    __shared__ float scell[9];
    __shared__ float snc[9];
    __shared__ float sred[Nn][10];

    if (n == 0) {
        float c[9];
        #pragma unroll
        for (int i = 0; i < 9; ++i) { c[i] = cell[b * 9 + i]; scell[i] = c[i]; }
        float det = c[0] * (c[4] * c[8] - c[5] * c[7])
                  - c[1] * (c[3] * c[8] - c[5] * c[6])
                  + c[2] * (c[3] * c[7] - c[4] * c[6]);
        float id = 1.0f / det;
        sinv[0] = (c[4] * c[8] - c[5] * c[7]) * id;
        sinv[1] = (c[2] * c[7] - c[1] * c[8]) * id;
        sinv[2] = (c[1] * c[5] - c[2] * c[4]) * id;
        sinv[3] = (c[5] * c[6] - c[3] * c[8]) * id;
        sinv[4] = (c[0] * c[8] - c[2] * c[6]) * id;
        sinv[5] = (c[2] * c[3] - c[0] * c[5]) * id;
        sinv[6] = (c[3] * c[7] - c[4] * c[6]) * id;
        sinv[7] = (c[1] * c[6] - c[0] * c[7]) * id;
        sinv[8] = (c[0] * c[4] - c[1] * c[3]) * id;
    }
    __syncthreads();

    float xv0 = 0.f, xv1 = 0.f, xv2 = 0.f;
    const int row = (b * Nn + n) * Ff;
    for (int ff = 0; ff < Ff; ++ff) {
        float xr = x[row + ff];
        xv0 = fmaf(xr, fdw[ff * 3 + 0], xv0);
        xv1 = fmaf(xr, fdw[ff * 3 + 1], xv1);
        xv2 = fmaf(xr, fdw[ff * 3 + 2], xv2);
    }
    float fr[3];
    float dsp[3] = {xv0, xv1, xv2};
    const float p0 = pos[(b * Nn + n) * 3 + 0];
    const float p1 = pos[(b * Nn + n) * 3 + 1];
    const float p2 = pos[(b * Nn + n) * 3 + 2];
    #pragma unroll
    for (int j = 0; j < 3; ++j) {
        float z = 10.0f * (dsp[j] + fdb[j]);
        float s = 1.0f / (1.0f + expf(-z));
        float fx = p0 * sinv[0 * 3 + j] + p1 * sinv[1 * 3 + j] + p2 * sinv[2 * 3 + j] + s;
        fr[j] = fx - floorf(fx);
    }

    float rep[3];
    #pragma unroll
    for (int j = 0; j < 3; ++j)
        rep[j] = fr[0] * scell[0 * 3 + j] + fr[1] * scell[1 * 3 + j] + fr[2] * scell[2 * 3 + j];

    float a6[6];
    #pragma unroll
    for (int i = 0; i < 6; ++i) {
        float uv = rep[0] * pw1[0 * 6 + i] + rep[1] * pw1[1 * 6 + i]
                 + rep[2] * pw1[2 * 6 + i] + pb1[i];
        a6[i] = ssp_f(uv);
    }
    float h9[9];
    #pragma unroll
    for (int o = 0; o < 9; ++o) {
        float uv = pb2[o];
        #pragma unroll
        for (int i = 0; i < 6; ++i) uv = fmaf(a6[i], pw2[i * 9 + o], uv);
        h9[o] = uv;
    }

    const float m = amask[b * Nn + n];
    #pragma unroll
    for (int o = 0; o < 9; ++o) sred[n][o] = h9[o] * m;
    sred[n][9] = m;
    __syncthreads();

    for (int s = 64; s >= 1; s >>= 1) {
        if (n < s) {
            #pragma unroll
            for (int o = 0; o < 10; ++o) sred[n][o] += sred[n + s][o];
        }
        __syncthreads();
    }

    if (n < 9) {
        float na = sred[0][9];
        float yo = sred[0][n] / na;
        float scale = 3.0f * powf(na, 1.0f / 3.0f);
        int r = n / 3, c = n - r * 3;
        float v = scale * (((r == c) ? 1.0f : 0.0f) + yo);
        snc[n] = v;
        out_cell[b * 9 + n] = v;
    }
    __syncthreads();

    #pragma unroll
    for (int j = 0; j < 3; ++j) {
        float v = fr[0] * snc[0 * 3 + j] + fr[1] * snc[1 * 3 + j] + fr[2] * snc[2 * 3 + j];
        out_pos[(b * Nn + n) * 3 + j] = v;
    }
}

// ---------------------------------------------------------------------------
extern "C" void kernel_launch(void* const* d_in, const int* in_sizes, int n_in,
                              void* d_out, int out_size, void* d_ws, size_t ws_size,
                              hipStream_t stream)
{
    const float* positions     = (const float*)d_in[0];
    const float* cell          = (const float*)d_in[1];
    const int*   atomic_nums   = (const int*)  d_in[2];
    const int*   neighbors     = (const int*)  d_in[3];
    const float* neighbor_mask = (const float*)d_in[4];
    const float* atom_mask     = (const float*)d_in[5];
    const float* embedding     = (const float*)d_in[6];
    const float* filt_w1       = (const float*)d_in[7];
    const float* filt_b1       = (const float*)d_in[8];
    const float* filt_w2       = (const float*)d_in[9];
    const float* filt_b2       = (const float*)d_in[10];
    const float* in2f_w        = (const float*)d_in[11];
    const float* f2out_w1      = (const float*)d_in[12];
    const float* f2out_b1      = (const float*)d_in[13];
    const float* f2out_w2      = (const float*)d_in[14];
    const float* f2out_b2      = (const float*)d_in[15];
    const float* fd_w          = (const float*)d_in[16];
    const float* fd_b          = (const float*)d_in[17];
    const float* pred_w1       = (const float*)d_in[18];
    const float* pred_b1       = (const float*)d_in[19];
    const float* pred_w2       = (const float*)d_in[20];
    const float* pred_b2       = (const float*)d_in[21];

    float* ws   = (float*)d_ws;
    float* x    = ws;
    float* y    = x + Bb * Nn * Ff;
    float* fexp = y + Bb * Nn * Ff;
    float* fcut = fexp + Bb * Nn * Kk * Gg;

    float* out_pos  = (float*)d_out;
    float* out_cell = out_pos + Bb * Nn * 3;

    const int BN = Bb * Nn;

    k_setup<<<BN, 256, 0, stream>>>(positions, atomic_nums, neighbors,
                                    neighbor_mask, embedding, x, fexp, fcut);

    for (int t = 0; t < Tt; ++t) {
        k_y<<<BN, 256, 0, stream>>>(x, in2f_w + (size_t)t * Ff * Ff, y);
        k_agg3<<<BN, 256, 0, stream>>>(fexp, fcut, neighbors, y,
                                       filt_w1 + (size_t)t * Gg * Ff,
                                       filt_b1 + (size_t)t * Ff,
                                       filt_w2 + (size_t)t * Ff * Ff,
                                       filt_b2 + (size_t)t * Ff,
                                       f2out_w1 + (size_t)t * Ff * Ff,
                                       f2out_b1 + (size_t)t * Ff,
                                       f2out_w2 + (size_t)t * Ff * Ff,
                                       f2out_b2 + (size_t)t * Ff,
                                       x);
    }

    k_head<<<Bb, 128, 0, stream>>>(x, positions, cell, atom_mask,
                                   fd_w, fd_b, pred_w1, pred_b1, pred_w2, pred_b2,
                                   out_pos, out_cell);
}